// Round 4
// baseline (22113.312 us; speedup 1.0000x reference)
//
#include <hip/hip_runtime.h>
#include <cstdio>

typedef __bf16 bf16x8 __attribute__((ext_vector_type(8)));
typedef float f32x4 __attribute__((ext_vector_type(4)));

#define DEV __device__ __forceinline__

DEV short f2bf(float f) {
    unsigned u = __builtin_bit_cast(unsigned, f);
    u += 0x7fffu + ((u >> 16) & 1u);   // RNE
    return (short)(u >> 16);
}
DEV float bf2f(short s) {
    unsigned u = ((unsigned)(unsigned short)s) << 16;
    return __builtin_bit_cast(float, u);
}
DEV float sigmoidf_(float x) { return 1.0f / (1.0f + __expf(-x)); }
DEV float tanhf_(float x) { float e = __expf(2.0f * x); return 1.0f - 2.0f / (e + 1.0f); }

DEV void gload_lds16(const void* g, void* l) {
    __builtin_amdgcn_global_load_lds(
        (__attribute__((address_space(1))) void*)(g),
        (__attribute__((address_space(3))) void*)(l), 16, 0, 0);
}

DEV f32x4 mfma16(bf16x8 a, bf16x8 b, f32x4 c) {
    return __builtin_amdgcn_mfma_f32_16x16x32_bf16(a, b, c, 0, 0, 0);
}

// ---------------- f32 -> bf16 convert ----------------
__global__ void f2bf_vec(const float* __restrict__ in, short* __restrict__ out, int n4) {
    int i = blockIdx.x * 256 + threadIdx.x;
    if (i >= n4) return;
    float4 v = reinterpret_cast<const float4*>(in)[i];
    short4 o;
    o.x = f2bf(v.x); o.y = f2bf(v.y); o.z = f2bf(v.z); o.w = f2bf(v.w);
    reinterpret_cast<short4*>(out)[i] = o;
}

// ---------------- pack Wh [1536][512] f32 into MFMA B-fragment order ----------------
// Wp[((gtile*16 + kk)*64 + lane)*8 + e] = bf16(Wh[(gtile*16 + (lane&15))*512 + kk*32 + (lane>>4)*8 + e])
__global__ void pack_wh(const float* __restrict__ Wh, short* __restrict__ Wp) {
    int tile = blockIdx.x, kk = blockIdx.y, l = threadIdx.x;  // 96 x 16, 64 thr
    int n = tile * 16 + (l & 15);
    int k0 = kk * 32 + (l >> 4) * 8;
    const float* src = Wh + (size_t)n * 512 + k0;
    short o[8];
#pragma unroll
    for (int e = 0; e < 8; e++) o[e] = f2bf(src[e]);
    *(int4*)(Wp + ((size_t)(tile * 16 + kk) * 64 + l) * 8) = *(int4*)o;
}

// ---------------- GEMM: C[m,n] = sum_k A[m,k] * W[n,k] + bias[n] ----------------
enum { M_XW1 = 0, M_UAW = 1, M_UAS = 2, M_XW2 = 3 };

template<int MODE>
__global__ __launch_bounds__(256) void gemm_bt(
    const short* __restrict__ Abase, const short* __restrict__ A2,
    const int* __restrict__ tok0, const int* __restrict__ tok1,
    const short* __restrict__ W, const float* __restrict__ bias,
    short* __restrict__ C, int M, int N, int K)
{
    __shared__ short Als[128 * 64];
    __shared__ short Bls[128 * 64];
    int tid = threadIdx.x;
    int m0 = blockIdx.y * 128, n0 = blockIdx.x * 128;
    int kc = (tid & 7) * 8;

    const short* arow[4];
#pragma unroll
    for (int i = 0; i < 4; i++) {
        int gm = m0 + i * 32 + (tid >> 3);
        if (MODE == M_XW1) {
            int t = gm >> 8, s = gm & 255;
            int tok = (s < 128) ? tok0[s * 256 + t] : tok1[(s - 128) * 256 + t];
            arow[i] = Abase + (size_t)tok * 512;
        } else if (MODE == M_UAW) {
            int t = gm >> 7, b = gm & 127;
            arow[i] = Abase + (size_t)tok0[b * 256 + t] * 512;
        } else if (MODE == M_UAS) {
            int t = gm >> 7, b = gm & 127;
            arow[i] = Abase + ((size_t)t * 256 + b) * 512;
        } else {
            arow[i] = Abase + (size_t)gm * 512;
        }
    }

    f32x4 acc[4][4] = {};
    int l = tid & 63, w = tid >> 6;
    int wm = (w >> 1) * 64, wn = (w & 1) * 64;

    for (int kt = 0; kt < K; kt += 64) {
#pragma unroll
        for (int i = 0; i < 4; i++) {
            const short* asrc;
            if (MODE == M_XW2) {
                int gm = m0 + i * 32 + (tid >> 3);
                const short* base = (kt < 512) ? Abase : A2;
                asrc = base + (size_t)gm * 512 + (kt & 511) + kc;
            } else {
                asrc = arow[i] + kt + kc;
            }
            gload_lds16(asrc, &Als[i * 2048 + tid * 8]);
        }
#pragma unroll
        for (int i = 0; i < 4; i++) {
            const short* bsrc = W + (size_t)(n0 + i * 32 + (tid >> 3)) * K + kt + kc;
            gload_lds16(bsrc, &Bls[i * 2048 + tid * 8]);
        }
        __syncthreads();
#pragma unroll
        for (int kk = 0; kk < 2; kk++) {
            int ko = kk * 32 + (l >> 4) * 8;
            bf16x8 af[4], bfr[4];
#pragma unroll
            for (int mi = 0; mi < 4; mi++)
                af[mi] = *(const bf16x8*)&Als[(wm + mi * 16 + (l & 15)) * 64 + ko];
#pragma unroll
            for (int ni = 0; ni < 4; ni++)
                bfr[ni] = *(const bf16x8*)&Bls[(wn + ni * 16 + (l & 15)) * 64 + ko];
#pragma unroll
            for (int mi = 0; mi < 4; mi++)
#pragma unroll
                for (int ni = 0; ni < 4; ni++)
                    acc[mi][ni] = mfma16(af[mi], bfr[ni], acc[mi][ni]);
        }
        __syncthreads();
    }
#pragma unroll
    for (int ni = 0; ni < 4; ni++) {
        int col = n0 + wn + ni * 16 + (l & 15);
        float bv = bias[col];
#pragma unroll
        for (int mi = 0; mi < 4; mi++) {
            int row0 = m0 + wm + mi * 16 + (l >> 4) * 4;
#pragma unroll
            for (int j = 0; j < 4; j++)
                C[(size_t)(row0 + j) * N + col] = f2bf(acc[mi][ni][j] + bv);
        }
    }
}

// ---------------- GRU scan v4: bulk-DMA Wh streaming ----------------
// One wg = 16 rows x all 512 h-cols, 1024 threads (16 waves).
// Wave w owns h-coltiles {2w, 2w+1}: 2 coltiles x 3 gates = 6 MFMAs per kk.
// Per kk-slice (K=32): all 96 B-gtile fragments (96 KB) DMA'd into LDS via
// global_load_lds (queue-based, no VGPR landing), __syncthreads drain (compiler
// emits vmcnt(0) before s_barrier), then 6 MFMAs/wave from LDS.
// h state: single 16 KB XOR-swizzled LDS buffer; read-phase/write-phase split by barrier.
// Per-step floor = B-stream 1.5 MB / per-CU L2 BW (~64 B/cyc) ~= 10-12 us.
DEV int hswz(int row, int colbyte) { return row * 1024 + (colbyte ^ ((row & 7) << 4)); }

template<int WRITE_ALL>
__global__ __launch_bounds__(1024) void gru_scan4(
    const short* __restrict__ xW,   // [T][S][1536] bf16 (includes bi)
    const short* __restrict__ Wp,   // packed Wh fragments [96 gtiles][16 kk][64 lane][8] bf16
    const float* __restrict__ bh,   // [1536]
    short* __restrict__ h_all,      // [T][S][512] bf16 (WRITE_ALL)
    float* __restrict__ h_final,    // [S][512] f32 (!WRITE_ALL, t==T-1)
    int S, int T)
{
    __shared__ char hl[16 * 1024];     // [16 rows][512 bf16], swizzled (16 KB)
    __shared__ char bb[96 * 1024];     // one kk-slice of B fragments (96 KB)
    int r0 = blockIdx.x * 16;
    int tid = threadIdx.x;
    int w = tid >> 6, l = tid & 63;
    int lrow = l & 15, lq = l >> 4;

    for (int i = tid; i < 16 * 1024 / 16; i += 1024)
        ((int4*)hl)[i] = int4{0, 0, 0, 0};
    __syncthreads();

    float bhv[2][3];
#pragma unroll
    for (int ctl = 0; ctl < 2; ctl++)
#pragma unroll
        for (int g = 0; g < 3; g++)
            bhv[ctl][g] = bh[g * 512 + (2 * w + ctl) * 16 + lrow];

    for (int t = 0; t < T; t++) {
        // xW for this step (consumed in gate phase; latency overlaps MFMA loop)
        short xrv[2][4], xzv[2][4], xnv[2][4];
        const short* xbase = xW + ((size_t)t * S + r0) * 1536;
#pragma unroll
        for (int ctl = 0; ctl < 2; ctl++)
#pragma unroll
            for (int j = 0; j < 4; j++) {
                const short* xp = xbase + (lq * 4 + j) * 1536 + (2 * w + ctl) * 16 + lrow;
                xrv[ctl][j] = xp[0];
                xzv[ctl][j] = xp[512];
                xnv[ctl][j] = xp[1024];
            }

        f32x4 acc[2][3] = {};
        float hp[2][4] = {};
        if (t > 0) {
            for (int kk = 0; kk < 16; kk++) {
                // stage slice kk: wave w DMAs gtiles w*6 .. w*6+5 (1 KB each)
#pragma unroll
                for (int j = 0; j < 6; j++) {
                    int gtile = w * 6 + j;
                    gload_lds16(Wp + ((size_t)(gtile * 16 + kk) * 64 + l) * 8,
                                bb + gtile * 1024 + l * 16);
                }
                __syncthreads();   // drains DMA queue (vmcnt(0) before s_barrier)
                bf16x8 a = *(const bf16x8*)(hl + hswz(lrow, (kk * 32 + lq * 8) * 2));
#pragma unroll
                for (int ctl = 0; ctl < 2; ctl++)
#pragma unroll
                    for (int g = 0; g < 3; g++) {
                        bf16x8 bfr = *(const bf16x8*)(bb + (g * 32 + 2 * w + ctl) * 1024 + l * 16);
                        acc[ctl][g] = mfma16(a, bfr, acc[ctl][g]);
                    }
                __syncthreads();   // all reads of bb done before next slice's DMA
            }
            // own previous-h cells (for z*h term)
#pragma unroll
            for (int ctl = 0; ctl < 2; ctl++)
#pragma unroll
                for (int j = 0; j < 4; j++)
                    hp[ctl][j] = bf2f(*(const short*)(hl + hswz(lq * 4 + j, ((2 * w + ctl) * 16 + lrow) * 2)));
        }
        __syncthreads();   // h_prev reads complete before h_new writes

        // gate phase
#pragma unroll
        for (int ctl = 0; ctl < 2; ctl++) {
#pragma unroll
            for (int j = 0; j < 4; j++) {
                int row = lq * 4 + j, col = (2 * w + ctl) * 16 + lrow;
                float r = sigmoidf_(bf2f(xrv[ctl][j]) + bhv[ctl][0] + acc[ctl][0][j]);
                float z = sigmoidf_(bf2f(xzv[ctl][j]) + bhv[ctl][1] + acc[ctl][1][j]);
                float n = tanhf_(bf2f(xnv[ctl][j]) + r * (acc[ctl][2][j] + bhv[ctl][2]));
                float h = (1.f - z) * n + z * hp[ctl][j];
                short hb = f2bf(h);
                *(short*)(hl + hswz(row, col * 2)) = hb;
                if (WRITE_ALL) h_all[((size_t)t * S + r0 + row) * 512 + col] = hb;
                else if (t == T - 1) h_final[(size_t)(r0 + row) * 512 + col] = h;
            }
        }
        __syncthreads();
    }
}

// ---------------- per-(b) sums: u_all_sum ----------------
__global__ void embed_sum_k(const short* __restrict__ ebf, const int* __restrict__ tok,
                            float* __restrict__ out) {
    int b = blockIdx.x, d = threadIdx.x;
    float a0 = 0.f, a1 = 0.f;
    for (int t = 0; t < 256; t++) {
        const short* row = ebf + (size_t)tok[b * 256 + t] * 512;
        a0 += bf2f(row[d]); a1 += bf2f(row[d + 256]);
    }
    out[b * 512 + d] = a0; out[b * 512 + d + 256] = a1;
}
__global__ void hall_sum_k(const short* __restrict__ h_all, float* __restrict__ out) {
    int b = blockIdx.x, d = threadIdx.x;
    float a0 = 0.f, a1 = 0.f;
    for (int t = 0; t < 256; t++) {
        const short* row = h_all + ((size_t)t * 256 + b) * 512;
        a0 += bf2f(row[d]); a1 += bf2f(row[d + 256]);
    }
    out[b * 512 + d] = a0; out[b * 512 + d + 256] = a1;
}

// ---------------- dual attention combine (one wave per (t,b)) ----------------
template<int WORD>
__global__ __launch_bounds__(256) void attn_combine(
    const short* __restrict__ uA, const short* __restrict__ rsrc,
    const int* __restrict__ rtok, const float* __restrict__ usum,
    const float* __restrict__ Wv, short* __restrict__ ctx)
{
    int l = threadIdx.x & 63, w = threadIdx.x >> 6;
    int m = blockIdx.x * 4 + w;
    int t = m >> 7, b = m & 127;
    const short* rrow;
    if (WORD) rrow = rsrc + (size_t)rtok[b * 256 + t] * 512;
    else      rrow = rsrc + ((size_t)t * 256 + 128 + b) * 512;
    const short* urow = uA + (size_t)m * 512;
    int d0 = l * 8;
    short ru[8], uu[8];
    *(int4*)ru = *(const int4*)(rrow + d0);
    *(int4*)uu = *(const int4*)(urow + d0);
    float rv[8], dot = 0.f;
#pragma unroll
    for (int i = 0; i < 8; i++) { rv[i] = bf2f(ru[i]); dot += rv[i] * bf2f(uu[i]); }
#pragma unroll
    for (int off = 32; off >= 1; off >>= 1) dot += __shfl_xor(dot, off);
    float tw = tanhf_(dot);
    float e[8], se = 0.f;
#pragma unroll
    for (int i = 0; i < 8; i++) { e[i] = __expf(tw * Wv[d0 + i]); se += e[i]; }
#pragma unroll
    for (int off = 32; off >= 1; off >>= 1) se += __shfl_xor(se, off);
    float inv = 1.f / se;
    short ov[8];
#pragma unroll
    for (int i = 0; i < 8; i++) ov[i] = f2bf(e[i] * inv * usum[b * 512 + d0 + i] * rv[i]);
    *(int4*)(ctx + (size_t)m * 512 + d0) = *(int4*)ov;
}

// ---------------- final classifier + softmax ----------------
__global__ void final_head_k(const float* __restrict__ h2, const float* __restrict__ Wf,
                             const float* __restrict__ bfv, float* __restrict__ out) {
    int b = blockIdx.x, l = threadIdx.x;  // 64 threads
    float d0 = 0.f, d1 = 0.f;
    for (int k = l; k < 512; k += 64) {
        float h = h2[b * 512 + k];
        d0 += h * Wf[k];
        d1 += h * Wf[512 + k];
    }
#pragma unroll
    for (int off = 32; off >= 1; off >>= 1) { d0 += __shfl_xor(d0, off); d1 += __shfl_xor(d1, off); }
    if (l == 0) {
        float l0 = d0 + bfv[0], l1 = d1 + bfv[1];
        float mx = fmaxf(l0, l1);
        float e0 = __expf(l0 - mx), e1 = __expf(l1 - mx);
        float s = e0 + e1;
        out[b * 2] = e0 / s; out[b * 2 + 1] = e1 / s;
    }
}

extern "C" void kernel_launch(void* const* d_in, const int* in_sizes, int n_in,
                              void* d_out, int out_size, void* d_ws, size_t ws_size,
                              hipStream_t stream)
{
    const int* ask    = (const int*)d_in[0];
    const int* answer = (const int*)d_in[1];
    const int* askkw  = (const int*)d_in[2];
    const int* anskw  = (const int*)d_in[3];
    const float* embed = (const float*)d_in[4];
    const float* Wi1 = (const float*)d_in[5];
    const float* Wh1 = (const float*)d_in[6];
    const float* bi1 = (const float*)d_in[7];
    const float* bh1 = (const float*)d_in[8];
    const float* Aw  = (const float*)d_in[9];
    const float* bw  = (const float*)d_in[10];
    const float* Ww  = (const float*)d_in[11];
    const float* As  = (const float*)d_in[12];
    const float* bs  = (const float*)d_in[13];
    const float* Ws  = (const float*)d_in[14];
    const float* Wi2 = (const float*)d_in[15];
    const float* Wh2 = (const float*)d_in[16];
    const float* bi2 = (const float*)d_in[17];
    const float* bh2 = (const float*)d_in[18];
    const float* Wf  = (const float*)d_in[19];
    const float* bfv = (const float*)d_in[20];

    char* ws = (char*)d_ws;
    size_t off = 0;
    auto alloc = [&](size_t bytes) -> void* {
        void* p = (void*)(ws + off);
        off += (bytes + 255) & ~(size_t)255;
        return p;
    };
    short* embed_bf = (short*)alloc(50000ULL * 512 * 2);
    short* Wi1b = (short*)alloc(1536 * 512 * 2);
    short* Wp1  = (short*)alloc(1536 * 512 * 2);   // packed Wh1 fragments
    short* Awb  = (short*)alloc(512 * 512 * 2);
    short* Asb  = (short*)alloc(512 * 512 * 2);
    short* Wi2b = (short*)alloc(1536 * 1024 * 2);
    short* Wp2  = (short*)alloc(1536 * 512 * 2);   // packed Wh2 fragments
    char* X = (char*)alloc(201326592ULL);            // xW1 region, reused after GRU1
    short* xW1  = (short*)X;                         // [256][256][1536] bf16
    short* uA   = (short*)X;                         // [32768][512] bf16 (after GRU1)
    short* ctxW = (short*)(X + 33554432);            // [256][128][512] bf16
    short* ctxS = (short*)(X + 67108864);            // [256][128][512] bf16
    short* xW2  = (short*)(X + 100663296);           // [256][128][1536] bf16
    short* h_all = (short*)alloc(256ULL * 256 * 512 * 2);  // [t][s][512] bf16
    float* usumW = (float*)alloc(128 * 512 * 4);
    float* usumS = (float*)alloc(128 * 512 * 4);
    float* h2f   = (float*)alloc(128 * 512 * 4);

    if (off > ws_size) {
        fprintf(stderr, "kernel_launch: workspace too small: need %zu have %zu\n", off, ws_size);
        return;
    }

    auto cv = [&](const float* src, short* dst, int n) {
        int n4 = n / 4;
        f2bf_vec<<<(n4 + 255) / 256, 256, 0, stream>>>(src, dst, n4);
    };
    cv(embed, embed_bf, 50000 * 512);
    cv(Wi1, Wi1b, 1536 * 512);
    cv(Aw, Awb, 512 * 512);
    cv(As, Asb, 512 * 512);
    cv(Wi2, Wi2b, 1536 * 1024);
    pack_wh<<<dim3(96, 16), 64, 0, stream>>>(Wh1, Wp1);
    pack_wh<<<dim3(96, 16), 64, 0, stream>>>(Wh2, Wp2);

    // xW1 = gathered embeds @ Wi1^T + bi1, rows m = t*256 + s  (s<128: ask, else answer)
    gemm_bt<M_XW1><<<dim3(12, 512), 256, 0, stream>>>(
        embed_bf, nullptr, ask, answer, Wi1b, bi1, xW1, 65536, 1536, 512);

    // GRU1 over ask+ans combined (S=256): 16 wgs, no cross-wg dependencies
    gru_scan4<1><<<16, 1024, 0, stream>>>(xW1, Wp1, bh1, h_all, nullptr, 256, 256);

    // word attention
    embed_sum_k<<<128, 256, 0, stream>>>(embed_bf, askkw, usumW);
    gemm_bt<M_UAW><<<dim3(4, 256), 256, 0, stream>>>(
        embed_bf, nullptr, askkw, nullptr, Awb, bw, uA, 32768, 512, 512);
    attn_combine<1><<<8192, 256, 0, stream>>>(uA, embed_bf, anskw, usumW, Ww, ctxW);

    // seq attention
    hall_sum_k<<<128, 256, 0, stream>>>(h_all, usumS);
    gemm_bt<M_UAS><<<dim3(4, 256), 256, 0, stream>>>(
        h_all, nullptr, nullptr, nullptr, Asb, bs, uA, 32768, 512, 512);
    attn_combine<0><<<8192, 256, 0, stream>>>(uA, h_all, nullptr, usumS, Ws, ctxS);

    // xW2 = [ctxW | ctxS] @ Wi2^T + bi2, rows m = t*128 + b
    gemm_bt<M_XW2><<<dim3(12, 256), 256, 0, stream>>>(
        ctxW, ctxS, nullptr, nullptr, Wi2b, bi2, xW2, 32768, 1536, 1024);

    // GRU2 (S=128): 8 wgs, keep only final hidden state
    gru_scan4<0><<<8, 1024, 0, stream>>>(xW2, Wp2, bh2, nullptr, h2f, 128, 256);

    final_head_k<<<128, 64, 0, stream>>>(h2f, Wf, bfv, (float*)d_out);
}

// Round 5
// 5201.081 us; speedup vs baseline: 4.2517x; 4.2517x over previous
//
#include <hip/hip_runtime.h>
#include <cstdio>

typedef __bf16 bf16x8 __attribute__((ext_vector_type(8)));
typedef float f32x4 __attribute__((ext_vector_type(4)));

#define DEV __device__ __forceinline__

DEV short f2bf(float f) {
    unsigned u = __builtin_bit_cast(unsigned, f);
    u += 0x7fffu + ((u >> 16) & 1u);   // RNE
    return (short)(u >> 16);
}
DEV float bf2f(short s) {
    unsigned u = ((unsigned)(unsigned short)s) << 16;
    return __builtin_bit_cast(float, u);
}
DEV float sigmoidf_(float x) { return 1.0f / (1.0f + __expf(-x)); }
DEV float tanhf_(float x) { float e = __expf(2.0f * x); return 1.0f - 2.0f / (e + 1.0f); }

DEV void gload_lds16(const void* g, void* l) {
    __builtin_amdgcn_global_load_lds(
        (__attribute__((address_space(1))) void*)(g),
        (__attribute__((address_space(3))) void*)(l), 16, 0, 0);
}

DEV f32x4 mfma16(bf16x8 a, bf16x8 b, f32x4 c) {
    return __builtin_amdgcn_mfma_f32_16x16x32_bf16(a, b, c, 0, 0, 0);
}

// ---------------- f32 -> bf16 convert ----------------
__global__ void f2bf_vec(const float* __restrict__ in, short* __restrict__ out, int n4) {
    int i = blockIdx.x * 256 + threadIdx.x;
    if (i >= n4) return;
    float4 v = reinterpret_cast<const float4*>(in)[i];
    short4 o;
    o.x = f2bf(v.x); o.y = f2bf(v.y); o.z = f2bf(v.z); o.w = f2bf(v.w);
    reinterpret_cast<short4*>(out)[i] = o;
}

// ---------------- pack Wh [1536][512] f32 into MFMA B-fragment order ----------------
// Wp[((gtile*16 + kk)*64 + lane)*8 + e] = bf16(Wh[(gtile*16 + (lane&15))*512 + kk*32 + (lane>>4)*8 + e])
__global__ void pack_wh(const float* __restrict__ Wh, short* __restrict__ Wp) {
    int tile = blockIdx.x, kk = blockIdx.y, l = threadIdx.x;  // 96 x 16, 64 thr
    int n = tile * 16 + (l & 15);
    int k0 = kk * 32 + (l >> 4) * 8;
    const float* src = Wh + (size_t)n * 512 + k0;
    short o[8];
#pragma unroll
    for (int e = 0; e < 8; e++) o[e] = f2bf(src[e]);
    *(int4*)(Wp + ((size_t)(tile * 16 + kk) * 64 + l) * 8) = *(int4*)o;
}

// ---------------- GEMM: C[m,n] = sum_k A[m,k] * W[n,k] + bias[n] ----------------
enum { M_XW1 = 0, M_UAW = 1, M_UAS = 2, M_XW2 = 3 };

template<int MODE>
__global__ __launch_bounds__(256) void gemm_bt(
    const short* __restrict__ Abase, const short* __restrict__ A2,
    const int* __restrict__ tok0, const int* __restrict__ tok1,
    const short* __restrict__ W, const float* __restrict__ bias,
    short* __restrict__ C, int M, int N, int K)
{
    __shared__ short Als[128 * 64];
    __shared__ short Bls[128 * 64];
    int tid = threadIdx.x;
    int m0 = blockIdx.y * 128, n0 = blockIdx.x * 128;
    int kc = (tid & 7) * 8;

    const short* arow[4];
#pragma unroll
    for (int i = 0; i < 4; i++) {
        int gm = m0 + i * 32 + (tid >> 3);
        if (MODE == M_XW1) {
            int t = gm >> 8, s = gm & 255;
            int tok = (s < 128) ? tok0[s * 256 + t] : tok1[(s - 128) * 256 + t];
            arow[i] = Abase + (size_t)tok * 512;
        } else if (MODE == M_UAW) {
            int t = gm >> 7, b = gm & 127;
            arow[i] = Abase + (size_t)tok0[b * 256 + t] * 512;
        } else if (MODE == M_UAS) {
            int t = gm >> 7, b = gm & 127;
            arow[i] = Abase + ((size_t)t * 256 + b) * 512;
        } else {
            arow[i] = Abase + (size_t)gm * 512;
        }
    }

    f32x4 acc[4][4] = {};
    int l = tid & 63, w = tid >> 6;
    int wm = (w >> 1) * 64, wn = (w & 1) * 64;

    for (int kt = 0; kt < K; kt += 64) {
#pragma unroll
        for (int i = 0; i < 4; i++) {
            const short* asrc;
            if (MODE == M_XW2) {
                int gm = m0 + i * 32 + (tid >> 3);
                const short* base = (kt < 512) ? Abase : A2;
                asrc = base + (size_t)gm * 512 + (kt & 511) + kc;
            } else {
                asrc = arow[i] + kt + kc;
            }
            gload_lds16(asrc, &Als[i * 2048 + tid * 8]);
        }
#pragma unroll
        for (int i = 0; i < 4; i++) {
            const short* bsrc = W + (size_t)(n0 + i * 32 + (tid >> 3)) * K + kt + kc;
            gload_lds16(bsrc, &Bls[i * 2048 + tid * 8]);
        }
        __syncthreads();
#pragma unroll
        for (int kk = 0; kk < 2; kk++) {
            int ko = kk * 32 + (l >> 4) * 8;
            bf16x8 af[4], bfr[4];
#pragma unroll
            for (int mi = 0; mi < 4; mi++)
                af[mi] = *(const bf16x8*)&Als[(wm + mi * 16 + (l & 15)) * 64 + ko];
#pragma unroll
            for (int ni = 0; ni < 4; ni++)
                bfr[ni] = *(const bf16x8*)&Bls[(wn + ni * 16 + (l & 15)) * 64 + ko];
#pragma unroll
            for (int mi = 0; mi < 4; mi++)
#pragma unroll
                for (int ni = 0; ni < 4; ni++)
                    acc[mi][ni] = mfma16(af[mi], bfr[ni], acc[mi][ni]);
        }
        __syncthreads();
    }
#pragma unroll
    for (int ni = 0; ni < 4; ni++) {
        int col = n0 + wn + ni * 16 + (l & 15);
        float bv = bias[col];
#pragma unroll
        for (int mi = 0; mi < 4; mi++) {
            int row0 = m0 + wm + mi * 16 + (l >> 4) * 4;
#pragma unroll
            for (int j = 0; j < 4; j++)
                C[(size_t)(row0 + j) * N + col] = f2bf(acc[mi][ni][j] + bv);
        }
    }
}

// ---------------- GRU scan v5: LDS-resident Wh + per-row-group flag sync ----------------
// Grid = (16 col-blocks of 32 cols, S/32 row-groups), 256 threads (4 waves).
// Wave w: row-tile rt=w>>1 (16 rows), col-tile ct=w&1 (16 cols), all 3 gates.
// Wh slice (3x32x512 = 96 KB, packed fragments) LDS-resident for all 256 steps.
// h ping-pongs between two global buffers; each step stages this row-group's
// 32x512 slab into XOR-swizzled LDS via global_load_lds.
// Sync: one release-atomicAdd per wg per step on a per-row-group counter
// (dedicated 128B line); acquire-spin by tid0 (cg grid-sync fence pattern,
// proven cross-XCD-correct in round 1). Cooperative launch -> co-residency.
template<int WRITE_ALL>
__global__ __launch_bounds__(256, 1) void gru_scan5(
    const short* __restrict__ xW,   // [T][S][1536] bf16 (includes bi)
    const short* __restrict__ Wp,   // packed Wh fragments [96][16][64][8] bf16
    const float* __restrict__ bh,   // [1536]
    short* __restrict__ hb0, short* __restrict__ hb1,  // [S][512] bf16 ping-pong
    short* __restrict__ h_all,      // [T][S][512] bf16 (WRITE_ALL)
    float* __restrict__ h_final,    // [S][512] f32 (!WRITE_ALL, t==T-1)
    unsigned* __restrict__ cnt,     // per-row-group counters, stride 32 u32 (128B)
    int S, int T)
{
    __shared__ char wl[96 * 1024];   // Wh fragments [6 lg][16 kk][64 lane][16B]
    __shared__ char hsl[32 * 1024];  // h slab [32 rows][512 cols] bf16, XOR-swizzled

    int cb = blockIdx.x;             // col block (32 cols)
    int rg = blockIdx.y;             // row group (32 rows)
    int r0 = rg * 32;
    int tid = threadIdx.x;
    int w = tid >> 6, l = tid & 63;
    int rt = w >> 1, ct = w & 1;
    int lrow = l & 15, lq = l >> 4;
    int colg = cb * 32 + ct * 16 + lrow;        // this lane's output column
    unsigned* myc = cnt + rg * 32;

    // ---- stage Wh slice once: local gtile lg = g*2+c2 <-> global g*32 + cb*2 + c2 ----
    for (int rr = 0; rr < 24; rr++) {
        int flat = rr * 256 + tid;               // [0, 6144) 16B chunks
        int lane = flat & 63, kk = (flat >> 6) & 15, lg = flat >> 10;
        int g = lg >> 1, c2 = lg & 1;
        gload_lds16(Wp + (((size_t)(g * 32 + cb * 2 + c2) * 16 + kk) * 64 + lane) * 8,
                    wl + flat * 16);
    }
    float bhv[3];
#pragma unroll
    for (int g = 0; g < 3; g++) bhv[g] = bh[g * 512 + colg];
    __syncthreads();   // drains Wh DMA

    for (int t = 0; t < T; t++) {
        // xW for this lane's 4 cells — issued before the spin, consumed at gates
        short xrv[4], xzv[4], xnv[4];
        const short* xbase = xW + ((size_t)t * S + r0) * 1536 + colg;
#pragma unroll
        for (int j = 0; j < 4; j++) {
            const short* xp = xbase + (size_t)(rt * 16 + lq * 4 + j) * 1536;
            xrv[j] = xp[0]; xzv[j] = xp[512]; xnv[j] = xp[1024];
        }

        f32x4 acc[3] = {};
        float hp[4] = {};
        if (t > 0) {
            const short* hprev = ((t & 1) ? hb0 : hb1) + (size_t)r0 * 512;
            if (tid == 0) {
                unsigned tgt = 16u * (unsigned)t;
                while (__hip_atomic_load(myc, __ATOMIC_ACQUIRE, __HIP_MEMORY_SCOPE_AGENT) < tgt)
                    __builtin_amdgcn_s_sleep(2);
            }
            __syncthreads();
            // stage slab (32 KB): linear LDS dest, inverse-swizzled global source
            for (int rr = 0; rr < 8; rr++) {
                int L = (rr * 256 + tid) * 16;
                int r = L >> 10, csw = L & 1023;
                int c = csw ^ ((r & 7) << 4);
                gload_lds16((const char*)hprev + r * 1024 + c, hsl + L);
            }
            __syncthreads();
            // A fragments (this wave's 16-row tile), reused across 3 gates
            bf16x8 afr[16];
#pragma unroll
            for (int kk = 0; kk < 16; kk++) {
                int r = rt * 16 + lrow;
                int cbyte = kk * 64 + lq * 16;
                afr[kk] = *(const bf16x8*)(hsl + r * 1024 + (cbyte ^ ((r & 7) << 4)));
            }
            // own previous-h cells
#pragma unroll
            for (int j = 0; j < 4; j++) {
                int r = rt * 16 + lq * 4 + j;
                hp[j] = bf2f(*(const short*)(hsl + r * 1024 + ((colg * 2) ^ ((r & 7) << 4))));
            }
            // MFMA: 3 gates x 16 kk
#pragma unroll
            for (int g = 0; g < 3; g++) {
                const char* bbase = wl + (size_t)((g * 2 + ct) * 16) * 1024 + l * 16;
#pragma unroll
                for (int kk = 0; kk < 16; kk++) {
                    bf16x8 bfr = *(const bf16x8*)(bbase + kk * 1024);
                    acc[g] = mfma16(afr[kk], bfr, acc[g]);
                }
            }
        }

        // gates + write h_new
        short* hnew = (t & 1) ? hb1 : hb0;
#pragma unroll
        for (int j = 0; j < 4; j++) {
            int row = rt * 16 + lq * 4 + j;
            float r = sigmoidf_(bf2f(xrv[j]) + bhv[0] + acc[0][j]);
            float z = sigmoidf_(bf2f(xzv[j]) + bhv[1] + acc[1][j]);
            float n = tanhf_(bf2f(xnv[j]) + r * (acc[2][j] + bhv[2]));
            float h = (1.f - z) * n + z * hp[j];
            short hb = f2bf(h);
            hnew[(size_t)(r0 + row) * 512 + colg] = hb;
            if (WRITE_ALL) h_all[((size_t)t * S + r0 + row) * 512 + colg] = hb;
            else if (t == T - 1) h_final[(size_t)(r0 + row) * 512 + colg] = h;
        }
        // publish: all waves' stores drained by barrier, then release increment
        __syncthreads();
        if (tid == 0) {
            __threadfence();
            __hip_atomic_fetch_add(myc, 1u, __ATOMIC_RELEASE, __HIP_MEMORY_SCOPE_AGENT);
        }
    }
}

// ---------------- per-(b) sums: u_all_sum ----------------
__global__ void embed_sum_k(const short* __restrict__ ebf, const int* __restrict__ tok,
                            float* __restrict__ out) {
    int b = blockIdx.x, d = threadIdx.x;
    float a0 = 0.f, a1 = 0.f;
    for (int t = 0; t < 256; t++) {
        const short* row = ebf + (size_t)tok[b * 256 + t] * 512;
        a0 += bf2f(row[d]); a1 += bf2f(row[d + 256]);
    }
    out[b * 512 + d] = a0; out[b * 512 + d + 256] = a1;
}
__global__ void hall_sum_k(const short* __restrict__ h_all, float* __restrict__ out) {
    int b = blockIdx.x, d = threadIdx.x;
    float a0 = 0.f, a1 = 0.f;
    for (int t = 0; t < 256; t++) {
        const short* row = h_all + ((size_t)t * 256 + b) * 512;
        a0 += bf2f(row[d]); a1 += bf2f(row[d + 256]);
    }
    out[b * 512 + d] = a0; out[b * 512 + d + 256] = a1;
}

// ---------------- dual attention combine (one wave per (t,b)) ----------------
template<int WORD>
__global__ __launch_bounds__(256) void attn_combine(
    const short* __restrict__ uA, const short* __restrict__ rsrc,
    const int* __restrict__ rtok, const float* __restrict__ usum,
    const float* __restrict__ Wv, short* __restrict__ ctx)
{
    int l = threadIdx.x & 63, w = threadIdx.x >> 6;
    int m = blockIdx.x * 4 + w;
    int t = m >> 7, b = m & 127;
    const short* rrow;
    if (WORD) rrow = rsrc + (size_t)rtok[b * 256 + t] * 512;
    else      rrow = rsrc + ((size_t)t * 256 + 128 + b) * 512;
    const short* urow = uA + (size_t)m * 512;
    int d0 = l * 8;
    short ru[8], uu[8];
    *(int4*)ru = *(const int4*)(rrow + d0);
    *(int4*)uu = *(const int4*)(urow + d0);
    float rv[8], dot = 0.f;
#pragma unroll
    for (int i = 0; i < 8; i++) { rv[i] = bf2f(ru[i]); dot += rv[i] * bf2f(uu[i]); }
#pragma unroll
    for (int off = 32; off >= 1; off >>= 1) dot += __shfl_xor(dot, off);
    float tw = tanhf_(dot);
    float e[8], se = 0.f;
#pragma unroll
    for (int i = 0; i < 8; i++) { e[i] = __expf(tw * Wv[d0 + i]); se += e[i]; }
#pragma unroll
    for (int off = 32; off >= 1; off >>= 1) se += __shfl_xor(se, off);
    float inv = 1.f / se;
    short ov[8];
#pragma unroll
    for (int i = 0; i < 8; i++) ov[i] = f2bf(e[i] * inv * usum[b * 512 + d0 + i] * rv[i]);
    *(int4*)(ctx + (size_t)m * 512 + d0) = *(int4*)ov;
}

// ---------------- final classifier + softmax ----------------
__global__ void final_head_k(const float* __restrict__ h2, const float* __restrict__ Wf,
                             const float* __restrict__ bfv, float* __restrict__ out) {
    int b = blockIdx.x, l = threadIdx.x;  // 64 threads
    float d0 = 0.f, d1 = 0.f;
    for (int k = l; k < 512; k += 64) {
        float h = h2[b * 512 + k];
        d0 += h * Wf[k];
        d1 += h * Wf[512 + k];
    }
#pragma unroll
    for (int off = 32; off >= 1; off >>= 1) { d0 += __shfl_xor(d0, off); d1 += __shfl_xor(d1, off); }
    if (l == 0) {
        float l0 = d0 + bfv[0], l1 = d1 + bfv[1];
        float mx = fmaxf(l0, l1);
        float e0 = __expf(l0 - mx), e1 = __expf(l1 - mx);
        float s = e0 + e1;
        out[b * 2] = e0 / s; out[b * 2 + 1] = e1 / s;
    }
}

extern "C" void kernel_launch(void* const* d_in, const int* in_sizes, int n_in,
                              void* d_out, int out_size, void* d_ws, size_t ws_size,
                              hipStream_t stream)
{
    const int* ask    = (const int*)d_in[0];
    const int* answer = (const int*)d_in[1];
    const int* askkw  = (const int*)d_in[2];
    const int* anskw  = (const int*)d_in[3];
    const float* embed = (const float*)d_in[4];
    const float* Wi1 = (const float*)d_in[5];
    const float* Wh1 = (const float*)d_in[6];
    const float* bi1 = (const float*)d_in[7];
    const float* bh1 = (const float*)d_in[8];
    const float* Aw  = (const float*)d_in[9];
    const float* bw  = (const float*)d_in[10];
    const float* Ww  = (const float*)d_in[11];
    const float* As  = (const float*)d_in[12];
    const float* bs  = (const float*)d_in[13];
    const float* Ws  = (const float*)d_in[14];
    const float* Wi2 = (const float*)d_in[15];
    const float* Wh2 = (const float*)d_in[16];
    const float* bi2 = (const float*)d_in[17];
    const float* bh2 = (const float*)d_in[18];
    const float* Wf  = (const float*)d_in[19];
    const float* bfv = (const float*)d_in[20];

    char* ws = (char*)d_ws;
    size_t off = 0;
    auto alloc = [&](size_t bytes) -> void* {
        void* p = (void*)(ws + off);
        off += (bytes + 255) & ~(size_t)255;
        return p;
    };
    short* embed_bf = (short*)alloc(50000ULL * 512 * 2);
    short* Wi1b = (short*)alloc(1536 * 512 * 2);
    short* Wp1  = (short*)alloc(1536 * 512 * 2);   // packed Wh1 fragments
    short* Awb  = (short*)alloc(512 * 512 * 2);
    short* Asb  = (short*)alloc(512 * 512 * 2);
    short* Wi2b = (short*)alloc(1536 * 1024 * 2);
    short* Wp2  = (short*)alloc(1536 * 512 * 2);   // packed Wh2 fragments
    char* X = (char*)alloc(201326592ULL);            // xW1 region, reused after GRU1
    short* xW1  = (short*)X;                         // [256][256][1536] bf16
    short* uA   = (short*)X;                         // [32768][512] bf16 (after GRU1)
    short* ctxW = (short*)(X + 33554432);            // [256][128][512] bf16
    short* ctxS = (short*)(X + 67108864);            // [256][128][512] bf16
    short* xW2  = (short*)(X + 100663296);           // [256][128][1536] bf16
    short* h_all = (short*)alloc(256ULL * 256 * 512 * 2);  // [t][s][512] bf16
    short* hb0 = (short*)alloc(256 * 512 * 2);
    short* hb1 = (short*)alloc(256 * 512 * 2);
    float* usumW = (float*)alloc(128 * 512 * 4);
    float* usumS = (float*)alloc(128 * 512 * 4);
    float* h2f   = (float*)alloc(128 * 512 * 4);
    unsigned* cnts = (unsigned*)alloc(12 * 128);     // 8 GRU1 + 4 GRU2 counters, 128B apart

    if (off > ws_size) {
        fprintf(stderr, "kernel_launch: workspace too small: need %zu have %zu\n", off, ws_size);
        return;
    }

    // zero sync counters (replayed on every graph launch)
    hipMemsetAsync(cnts, 0, 12 * 128, stream);

    auto cv = [&](const float* src, short* dst, int n) {
        int n4 = n / 4;
        f2bf_vec<<<(n4 + 255) / 256, 256, 0, stream>>>(src, dst, n4);
    };
    cv(embed, embed_bf, 50000 * 512);
    cv(Wi1, Wi1b, 1536 * 512);
    cv(Aw, Awb, 512 * 512);
    cv(As, Asb, 512 * 512);
    cv(Wi2, Wi2b, 1536 * 1024);
    pack_wh<<<dim3(96, 16), 64, 0, stream>>>(Wh1, Wp1);
    pack_wh<<<dim3(96, 16), 64, 0, stream>>>(Wh2, Wp2);

    // xW1 = gathered embeds @ Wi1^T + bi1, rows m = t*256 + s  (s<128: ask, else answer)
    gemm_bt<M_XW1><<<dim3(12, 512), 256, 0, stream>>>(
        embed_bf, nullptr, ask, answer, Wi1b, bi1, xW1, 65536, 1536, 512);

    // GRU1 over ask+ans combined (S=256): 16 col-wgs x 8 row-groups
    {
        const short* xWa = xW1; const short* Wpa = Wp1; const float* bha = bh1;
        short* a0 = hb0; short* a1 = hb1; short* ha = h_all; float* hf = h2f;
        unsigned* cp = cnts; int S = 256, T = 256;
        void* args[] = { (void*)&xWa, (void*)&Wpa, (void*)&bha, (void*)&a0, (void*)&a1,
                         (void*)&ha, (void*)&hf, (void*)&cp, (void*)&S, (void*)&T };
        hipError_t e = hipLaunchCooperativeKernel(
            reinterpret_cast<void*>(&gru_scan5<1>), dim3(16, 8), dim3(256), args, 0, stream);
        if (e != hipSuccess)   // fallback: plain launch (128 wgs, 1/CU -> co-resident in practice)
            gru_scan5<1><<<dim3(16, 8), 256, 0, stream>>>(xWa, Wpa, bha, a0, a1, ha, hf, cp, S, T);
    }

    // word attention
    embed_sum_k<<<128, 256, 0, stream>>>(embed_bf, askkw, usumW);
    gemm_bt<M_UAW><<<dim3(4, 256), 256, 0, stream>>>(
        embed_bf, nullptr, askkw, nullptr, Awb, bw, uA, 32768, 512, 512);
    attn_combine<1><<<8192, 256, 0, stream>>>(uA, embed_bf, anskw, usumW, Ww, ctxW);

    // seq attention
    hall_sum_k<<<128, 256, 0, stream>>>(h_all, usumS);
    gemm_bt<M_UAS><<<dim3(4, 256), 256, 0, stream>>>(
        h_all, nullptr, nullptr, nullptr, Asb, bs, uA, 32768, 512, 512);
    attn_combine<0><<<8192, 256, 0, stream>>>(uA, h_all, nullptr, usumS, Ws, ctxS);

    // xW2 = [ctxW | ctxS] @ Wi2^T + bi2, rows m = t*128 + b
    gemm_bt<M_XW2><<<dim3(12, 256), 256, 0, stream>>>(
        ctxW, ctxS, nullptr, nullptr, Wi2b, bi2, xW2, 32768, 1536, 1024);

    // GRU2 (S=128): 16 col-wgs x 4 row-groups, keep only final hidden state
    {
        const short* xWa = xW2; const short* Wpa = Wp2; const float* bha = bh2;
        short* a0 = hb0; short* a1 = hb1; short* ha = nullptr; float* hf = h2f;
        unsigned* cp = cnts + 8 * 32; int S = 128, T = 256;
        void* args[] = { (void*)&xWa, (void*)&Wpa, (void*)&bha, (void*)&a0, (void*)&a1,
                         (void*)&ha, (void*)&hf, (void*)&cp, (void*)&S, (void*)&T };
        hipError_t e = hipLaunchCooperativeKernel(
            reinterpret_cast<void*>(&gru_scan5<0>), dim3(16, 4), dim3(256), args, 0, stream);
        if (e != hipSuccess)
            gru_scan5<0><<<dim3(16, 4), 256, 0, stream>>>(xWa, Wpa, bha, a0, a1, ha, hf, cp, S, T);
    }

    final_head_k<<<128, 64, 0, stream>>>(h2f, Wf, bfv, (float*)d_out);
}

// Round 6
// 4672.498 us; speedup vs baseline: 4.7327x; 1.1131x over previous
//
#include <hip/hip_runtime.h>
#include <cstdio>

typedef __bf16 bf16x8 __attribute__((ext_vector_type(8)));
typedef float f32x4 __attribute__((ext_vector_type(4)));

#define DEV __device__ __forceinline__

DEV short f2bf(float f) {
    unsigned u = __builtin_bit_cast(unsigned, f);
    u += 0x7fffu + ((u >> 16) & 1u);   // RNE
    return (short)(u >> 16);
}
DEV float bf2f(short s) {
    unsigned u = ((unsigned)(unsigned short)s) << 16;
    return __builtin_bit_cast(float, u);
}
DEV float sigmoidf_(float x) { return 1.0f / (1.0f + __expf(-x)); }
DEV float tanhf_(float x) { float e = __expf(2.0f * x); return 1.0f - 2.0f / (e + 1.0f); }

DEV void gload_lds16(const void* g, void* l) {
    __builtin_amdgcn_global_load_lds(
        (__attribute__((address_space(1))) void*)(g),
        (__attribute__((address_space(3))) void*)(l), 16, 0, 0);
}

DEV f32x4 mfma16(bf16x8 a, bf16x8 b, f32x4 c) {
    return __builtin_amdgcn_mfma_f32_16x16x32_bf16(a, b, c, 0, 0, 0);
}

// ---------------- f32 -> bf16 convert ----------------
__global__ void f2bf_vec(const float* __restrict__ in, short* __restrict__ out, int n4) {
    int i = blockIdx.x * 256 + threadIdx.x;
    if (i >= n4) return;
    float4 v = reinterpret_cast<const float4*>(in)[i];
    short4 o;
    o.x = f2bf(v.x); o.y = f2bf(v.y); o.z = f2bf(v.z); o.w = f2bf(v.w);
    reinterpret_cast<short4*>(out)[i] = o;
}

// ---------------- pack Wh [1536][512] f32 into MFMA B-fragment order ----------------
__global__ void pack_wh(const float* __restrict__ Wh, short* __restrict__ Wp) {
    int tile = blockIdx.x, kk = blockIdx.y, l = threadIdx.x;  // 96 x 16, 64 thr
    int n = tile * 16 + (l & 15);
    int k0 = kk * 32 + (l >> 4) * 8;
    const float* src = Wh + (size_t)n * 512 + k0;
    short o[8];
#pragma unroll
    for (int e = 0; e < 8; e++) o[e] = f2bf(src[e]);
    *(int4*)(Wp + ((size_t)(tile * 16 + kk) * 64 + l) * 8) = *(int4*)o;
}

// ---------------- GEMM: C[m,n] = sum_k A[m,k] * W[n,k] + bias[n] ----------------
enum { M_XW1 = 0, M_UAW = 1, M_UAS = 2, M_XW2 = 3 };

template<int MODE>
__global__ __launch_bounds__(256) void gemm_bt(
    const short* __restrict__ Abase, const short* __restrict__ A2,
    const int* __restrict__ tok0, const int* __restrict__ tok1,
    const short* __restrict__ W, const float* __restrict__ bias,
    short* __restrict__ C, int M, int N, int K)
{
    __shared__ short Als[128 * 64];
    __shared__ short Bls[128 * 64];
    int tid = threadIdx.x;
    int m0 = blockIdx.y * 128, n0 = blockIdx.x * 128;
    int kc = (tid & 7) * 8;

    const short* arow[4];
#pragma unroll
    for (int i = 0; i < 4; i++) {
        int gm = m0 + i * 32 + (tid >> 3);
        if (MODE == M_XW1) {
            int t = gm >> 8, s = gm & 255;
            int tok = (s < 128) ? tok0[s * 256 + t] : tok1[(s - 128) * 256 + t];
            arow[i] = Abase + (size_t)tok * 512;
        } else if (MODE == M_UAW) {
            int t = gm >> 7, b = gm & 127;
            arow[i] = Abase + (size_t)tok0[b * 256 + t] * 512;
        } else if (MODE == M_UAS) {
            int t = gm >> 7, b = gm & 127;
            arow[i] = Abase + ((size_t)t * 256 + b) * 512;
        } else {
            arow[i] = Abase + (size_t)gm * 512;
        }
    }

    f32x4 acc[4][4] = {};
    int l = tid & 63, w = tid >> 6;
    int wm = (w >> 1) * 64, wn = (w & 1) * 64;

    for (int kt = 0; kt < K; kt += 64) {
#pragma unroll
        for (int i = 0; i < 4; i++) {
            const short* asrc;
            if (MODE == M_XW2) {
                int gm = m0 + i * 32 + (tid >> 3);
                const short* base = (kt < 512) ? Abase : A2;
                asrc = base + (size_t)gm * 512 + (kt & 511) + kc;
            } else {
                asrc = arow[i] + kt + kc;
            }
            gload_lds16(asrc, &Als[i * 2048 + tid * 8]);
        }
#pragma unroll
        for (int i = 0; i < 4; i++) {
            const short* bsrc = W + (size_t)(n0 + i * 32 + (tid >> 3)) * K + kt + kc;
            gload_lds16(bsrc, &Bls[i * 2048 + tid * 8]);
        }
        __syncthreads();
#pragma unroll
        for (int kk = 0; kk < 2; kk++) {
            int ko = kk * 32 + (l >> 4) * 8;
            bf16x8 af[4], bfr[4];
#pragma unroll
            for (int mi = 0; mi < 4; mi++)
                af[mi] = *(const bf16x8*)&Als[(wm + mi * 16 + (l & 15)) * 64 + ko];
#pragma unroll
            for (int ni = 0; ni < 4; ni++)
                bfr[ni] = *(const bf16x8*)&Bls[(wn + ni * 16 + (l & 15)) * 64 + ko];
#pragma unroll
            for (int mi = 0; mi < 4; mi++)
#pragma unroll
                for (int ni = 0; ni < 4; ni++)
                    acc[mi][ni] = mfma16(af[mi], bfr[ni], acc[mi][ni]);
        }
        __syncthreads();
    }
#pragma unroll
    for (int ni = 0; ni < 4; ni++) {
        int col = n0 + wn + ni * 16 + (l & 15);
        float bv = bias[col];
#pragma unroll
        for (int mi = 0; mi < 4; mi++) {
            int row0 = m0 + wm + mi * 16 + (l >> 4) * 4;
#pragma unroll
            for (int j = 0; j < 4; j++)
                C[(size_t)(row0 + j) * N + col] = f2bf(acc[mi][ni][j] + bv);
        }
    }
}

// ---------------- GRU scan v6: LDS-resident Wh, register A-fragments, lean sync ----------------
// Grid = (16 col-blocks of 32 cols, S/32 row-groups), 256 threads (4 waves).
// Wave w: row-tile rt=w>>1 (16 rows), col-tile ct=w&1 (16 cols), 3 gates = 48 MFMA/step.
// Wh slice (96 KB packed fragments) LDS-resident for all steps. Previous h read
// DIRECTLY from global into registers (no LDS slab): correct because the acquire
// fence (one buffer_inv) precedes the loads; peer stores were flushed by the
// peer's release atomicAdd (one buffer_wbl2). One release + one acquire per step.
// h_all / h_final stores issued AFTER the publish (off the serial chain).
template<int WRITE_ALL>
__global__ __launch_bounds__(256, 1) void gru_scan6(
    const short* __restrict__ xW,   // [T][S][1536] bf16 (includes bi)
    const short* __restrict__ Wp,   // packed Wh fragments [96][16][64][8] bf16
    const float* __restrict__ bh,   // [1536]
    short* __restrict__ hb0, short* __restrict__ hb1,  // [S][512] bf16 ping-pong
    short* __restrict__ h_all,      // [T][S][512] bf16 (WRITE_ALL)
    float* __restrict__ h_final,    // [S][512] f32 (!WRITE_ALL, t==T-1)
    unsigned* __restrict__ cnt,     // per-row-group counters, stride 32 u32 (128B)
    int S, int T)
{
    __shared__ char wl[96 * 1024];   // Wh fragments [6 lg][16 kk][64 lane][16B]

    int cb = blockIdx.x;             // col block (32 cols)
    int rg = blockIdx.y;             // row group (32 rows)
    int r0 = rg * 32;
    int tid = threadIdx.x;
    int w = tid >> 6, l = tid & 63;
    int rt = w >> 1, ct = w & 1;
    int lrow = l & 15, lq = l >> 4;
    int colg = cb * 32 + ct * 16 + lrow;
    unsigned* myc = cnt + rg * 32;

    // stage Wh slice once: local gtile lg = g*2+c2 <-> global g*32 + cb*2 + c2
    for (int rr = 0; rr < 24; rr++) {
        int flat = rr * 256 + tid;               // [0, 6144) 16B chunks
        int lane = flat & 63, kk = (flat >> 6) & 15, lg = flat >> 10;
        int g = lg >> 1, c2 = lg & 1;
        gload_lds16(Wp + (((size_t)(g * 32 + cb * 2 + c2) * 16 + kk) * 64 + lane) * 8,
                    wl + flat * 16);
    }
    float bhv[3];
#pragma unroll
    for (int g = 0; g < 3; g++) bhv[g] = bh[g * 512 + colg];
    __syncthreads();   // drains Wh DMA

    for (int t = 0; t < T; t++) {
        // xW loads issued before the spin; values land in registers during the wait
        short xrv[4], xzv[4], xnv[4];
        const short* xbase = xW + ((size_t)t * S + r0) * 1536 + colg;
#pragma unroll
        for (int j = 0; j < 4; j++) {
            const short* xp = xbase + (size_t)(rt * 16 + lq * 4 + j) * 1536;
            xrv[j] = xp[0]; xzv[j] = xp[512]; xnv[j] = xp[1024];
        }

        f32x4 acc[3] = {};
        float hp[4] = {};
        if (t > 0) {
            const short* hprev = ((t & 1) ? hb0 : hb1) + (size_t)r0 * 512;
            if (tid == 0) {
                unsigned tgt = 16u * (unsigned)t;
                while (__hip_atomic_load(myc, __ATOMIC_RELAXED, __HIP_MEMORY_SCOPE_AGENT) < tgt)
                    __builtin_amdgcn_s_sleep(1);
                __builtin_amdgcn_fence(__ATOMIC_ACQUIRE, "agent");  // one buffer_inv
            }
            __syncthreads();
            // A fragments straight from global (64B-line aligned per 4-lane group)
            bf16x8 afr[16];
            const short* arow = hprev + (size_t)(rt * 16 + lrow) * 512;
#pragma unroll
            for (int kk = 0; kk < 16; kk++)
                afr[kk] = *(const bf16x8*)(arow + kk * 32 + lq * 8);
#pragma unroll
            for (int j = 0; j < 4; j++)
                hp[j] = bf2f(hprev[(size_t)(rt * 16 + lq * 4 + j) * 512 + colg]);
            // MFMA: 3 gates x 16 kk (B from LDS-resident Wh)
#pragma unroll
            for (int g = 0; g < 3; g++) {
                const char* bbase = wl + (size_t)((g * 2 + ct) * 16) * 1024 + l * 16;
#pragma unroll
                for (int kk = 0; kk < 16; kk++) {
                    bf16x8 bfr = *(const bf16x8*)(bbase + kk * 1024);
                    acc[g] = mfma16(afr[kk], bfr, acc[g]);
                }
            }
        }

        // gates + store h_new (on the chain), publish, then off-chain stores
        short* hnew = (t & 1) ? hb1 : hb0;
        float hv[4]; short hbv[4];
#pragma unroll
        for (int j = 0; j < 4; j++) {
            float r = sigmoidf_(bf2f(xrv[j]) + bhv[0] + acc[0][j]);
            float z = sigmoidf_(bf2f(xzv[j]) + bhv[1] + acc[1][j]);
            float n = tanhf_(bf2f(xnv[j]) + r * (acc[2][j] + bhv[2]));
            hv[j] = (1.f - z) * n + z * hp[j];
            hbv[j] = f2bf(hv[j]);
            hnew[(size_t)(r0 + rt * 16 + lq * 4 + j) * 512 + colg] = hbv[j];
        }
        __syncthreads();   // per-thread vmcnt(0) drain: all stores in L2 before release
        if (tid == 0)
            __hip_atomic_fetch_add(myc, 1u, __ATOMIC_RELEASE, __HIP_MEMORY_SCOPE_AGENT);
        if (WRITE_ALL) {
#pragma unroll
            for (int j = 0; j < 4; j++)
                h_all[((size_t)t * S + r0 + rt * 16 + lq * 4 + j) * 512 + colg] = hbv[j];
        } else if (t == T - 1) {
#pragma unroll
            for (int j = 0; j < 4; j++)
                h_final[(size_t)(r0 + rt * 16 + lq * 4 + j) * 512 + colg] = hv[j];
        }
    }
}

// ---------------- per-(b) sums: u_all_sum ----------------
__global__ void embed_sum_k(const short* __restrict__ ebf, const int* __restrict__ tok,
                            float* __restrict__ out) {
    int b = blockIdx.x, d = threadIdx.x;
    float a0 = 0.f, a1 = 0.f;
    for (int t = 0; t < 256; t++) {
        const short* row = ebf + (size_t)tok[b * 256 + t] * 512;
        a0 += bf2f(row[d]); a1 += bf2f(row[d + 256]);
    }
    out[b * 512 + d] = a0; out[b * 512 + d + 256] = a1;
}
__global__ void hall_sum_k(const short* __restrict__ h_all, float* __restrict__ out) {
    int b = blockIdx.x, d = threadIdx.x;
    float a0 = 0.f, a1 = 0.f;
    for (int t = 0; t < 256; t++) {
        const short* row = h_all + ((size_t)t * 256 + b) * 512;
        a0 += bf2f(row[d]); a1 += bf2f(row[d + 256]);
    }
    out[b * 512 + d] = a0; out[b * 512 + d + 256] = a1;
}

// ---------------- dual attention combine (one wave per (t,b)) ----------------
template<int WORD>
__global__ __launch_bounds__(256) void attn_combine(
    const short* __restrict__ uA, const short* __restrict__ rsrc,
    const int* __restrict__ rtok, const float* __restrict__ usum,
    const float* __restrict__ Wv, short* __restrict__ ctx)
{
    int l = threadIdx.x & 63, w = threadIdx.x >> 6;
    int m = blockIdx.x * 4 + w;
    int t = m >> 7, b = m & 127;
    const short* rrow;
    if (WORD) rrow = rsrc + (size_t)rtok[b * 256 + t] * 512;
    else      rrow = rsrc + ((size_t)t * 256 + 128 + b) * 512;
    const short* urow = uA + (size_t)m * 512;
    int d0 = l * 8;
    short ru[8], uu[8];
    *(int4*)ru = *(const int4*)(rrow + d0);
    *(int4*)uu = *(const int4*)(urow + d0);
    float rv[8], dot = 0.f;
#pragma unroll
    for (int i = 0; i < 8; i++) { rv[i] = bf2f(ru[i]); dot += rv[i] * bf2f(uu[i]); }
#pragma unroll
    for (int off = 32; off >= 1; off >>= 1) dot += __shfl_xor(dot, off);
    float tw = tanhf_(dot);
    float e[8], se = 0.f;
#pragma unroll
    for (int i = 0; i < 8; i++) { e[i] = __expf(tw * Wv[d0 + i]); se += e[i]; }
#pragma unroll
    for (int off = 32; off >= 1; off >>= 1) se += __shfl_xor(se, off);
    float inv = 1.f / se;
    short ov[8];
#pragma unroll
    for (int i = 0; i < 8; i++) ov[i] = f2bf(e[i] * inv * usum[b * 512 + d0 + i] * rv[i]);
    *(int4*)(ctx + (size_t)m * 512 + d0) = *(int4*)ov;
}

// ---------------- final classifier + softmax ----------------
__global__ void final_head_k(const float* __restrict__ h2, const float* __restrict__ Wf,
                             const float* __restrict__ bfv, float* __restrict__ out) {
    int b = blockIdx.x, l = threadIdx.x;  // 64 threads
    float d0 = 0.f, d1 = 0.f;
    for (int k = l; k < 512; k += 64) {
        float h = h2[b * 512 + k];
        d0 += h * Wf[k];
        d1 += h * Wf[512 + k];
    }
#pragma unroll
    for (int off = 32; off >= 1; off >>= 1) { d0 += __shfl_xor(d0, off); d1 += __shfl_xor(d1, off); }
    if (l == 0) {
        float l0 = d0 + bfv[0], l1 = d1 + bfv[1];
        float mx = fmaxf(l0, l1);
        float e0 = __expf(l0 - mx), e1 = __expf(l1 - mx);
        float s = e0 + e1;
        out[b * 2] = e0 / s; out[b * 2 + 1] = e1 / s;
    }
}

extern "C" void kernel_launch(void* const* d_in, const int* in_sizes, int n_in,
                              void* d_out, int out_size, void* d_ws, size_t ws_size,
                              hipStream_t stream)
{
    const int* ask    = (const int*)d_in[0];
    const int* answer = (const int*)d_in[1];
    const int* askkw  = (const int*)d_in[2];
    const int* anskw  = (const int*)d_in[3];
    const float* embed = (const float*)d_in[4];
    const float* Wi1 = (const float*)d_in[5];
    const float* Wh1 = (const float*)d_in[6];
    const float* bi1 = (const float*)d_in[7];
    const float* bh1 = (const float*)d_in[8];
    const float* Aw  = (const float*)d_in[9];
    const float* bw  = (const float*)d_in[10];
    const float* Ww  = (const float*)d_in[11];
    const float* As  = (const float*)d_in[12];
    const float* bs  = (const float*)d_in[13];
    const float* Ws  = (const float*)d_in[14];
    const float* Wi2 = (const float*)d_in[15];
    const float* Wh2 = (const float*)d_in[16];
    const float* bi2 = (const float*)d_in[17];
    const float* bh2 = (const float*)d_in[18];
    const float* Wf  = (const float*)d_in[19];
    const float* bfv = (const float*)d_in[20];

    char* ws = (char*)d_ws;
    size_t off = 0;
    auto alloc = [&](size_t bytes) -> void* {
        void* p = (void*)(ws + off);
        off += (bytes + 255) & ~(size_t)255;
        return p;
    };
    short* embed_bf = (short*)alloc(50000ULL * 512 * 2);
    short* Wi1b = (short*)alloc(1536 * 512 * 2);
    short* Wp1  = (short*)alloc(1536 * 512 * 2);   // packed Wh1 fragments
    short* Awb  = (short*)alloc(512 * 512 * 2);
    short* Asb  = (short*)alloc(512 * 512 * 2);
    short* Wi2b = (short*)alloc(1536 * 1024 * 2);
    short* Wp2  = (short*)alloc(1536 * 512 * 2);   // packed Wh2 fragments
    char* X = (char*)alloc(201326592ULL);            // xW1 region, reused after GRU1
    short* xW1  = (short*)X;                         // [256][256][1536] bf16
    short* uA   = (short*)X;                         // [32768][512] bf16 (after GRU1)
    short* ctxW = (short*)(X + 33554432);            // [256][128][512] bf16
    short* ctxS = (short*)(X + 67108864);            // [256][128][512] bf16
    short* xW2  = (short*)(X + 100663296);           // [256][128][1536] bf16
    short* h_all = (short*)alloc(256ULL * 256 * 512 * 2);  // [t][s][512] bf16
    short* hb0 = (short*)alloc(256 * 512 * 2);
    short* hb1 = (short*)alloc(256 * 512 * 2);
    float* usumW = (float*)alloc(128 * 512 * 4);
    float* usumS = (float*)alloc(128 * 512 * 4);
    float* h2f   = (float*)alloc(128 * 512 * 4);
    unsigned* cnts = (unsigned*)alloc(12 * 128);     // 8 GRU1 + 4 GRU2 counters, 128B apart

    if (off > ws_size) {
        fprintf(stderr, "kernel_launch: workspace too small: need %zu have %zu\n", off, ws_size);
        return;
    }

    // zero sync counters (replayed on every graph launch)
    hipMemsetAsync(cnts, 0, 12 * 128, stream);

    auto cv = [&](const float* src, short* dst, int n) {
        int n4 = n / 4;
        f2bf_vec<<<(n4 + 255) / 256, 256, 0, stream>>>(src, dst, n4);
    };
    cv(embed, embed_bf, 50000 * 512);
    cv(Wi1, Wi1b, 1536 * 512);
    cv(Aw, Awb, 512 * 512);
    cv(As, Asb, 512 * 512);
    cv(Wi2, Wi2b, 1536 * 1024);
    pack_wh<<<dim3(96, 16), 64, 0, stream>>>(Wh1, Wp1);
    pack_wh<<<dim3(96, 16), 64, 0, stream>>>(Wh2, Wp2);

    // xW1 = gathered embeds @ Wi1^T + bi1, rows m = t*256 + s  (s<128: ask, else answer)
    gemm_bt<M_XW1><<<dim3(12, 512), 256, 0, stream>>>(
        embed_bf, nullptr, ask, answer, Wi1b, bi1, xW1, 65536, 1536, 512);

    // GRU1 over ask+ans combined (S=256): 16 col-wgs x 8 row-groups
    {
        const short* xWa = xW1; const short* Wpa = Wp1; const float* bha = bh1;
        short* a0 = hb0; short* a1 = hb1; short* ha = h_all; float* hf = h2f;
        unsigned* cp = cnts; int S = 256, T = 256;
        void* args[] = { (void*)&xWa, (void*)&Wpa, (void*)&bha, (void*)&a0, (void*)&a1,
                         (void*)&ha, (void*)&hf, (void*)&cp, (void*)&S, (void*)&T };
        hipError_t e = hipLaunchCooperativeKernel(
            reinterpret_cast<void*>(&gru_scan6<1>), dim3(16, 8), dim3(256), args, 0, stream);
        if (e != hipSuccess)   // fallback: plain launch (128 wgs, 1/CU -> co-resident)
            gru_scan6<1><<<dim3(16, 8), 256, 0, stream>>>(xWa, Wpa, bha, a0, a1, ha, hf, cp, S, T);
    }

    // word attention
    embed_sum_k<<<128, 256, 0, stream>>>(embed_bf, askkw, usumW);
    gemm_bt<M_UAW><<<dim3(4, 256), 256, 0, stream>>>(
        embed_bf, nullptr, askkw, nullptr, Awb, bw, uA, 32768, 512, 512);
    attn_combine<1><<<8192, 256, 0, stream>>>(uA, embed_bf, anskw, usumW, Ww, ctxW);

    // seq attention
    hall_sum_k<<<128, 256, 0, stream>>>(h_all, usumS);
    gemm_bt<M_UAS><<<dim3(4, 256), 256, 0, stream>>>(
        h_all, nullptr, nullptr, nullptr, Asb, bs, uA, 32768, 512, 512);
    attn_combine<0><<<8192, 256, 0, stream>>>(uA, h_all, nullptr, usumS, Ws, ctxS);

    // xW2 = [ctxW | ctxS] @ Wi2^T + bi2, rows m = t*128 + b
    gemm_bt<M_XW2><<<dim3(12, 256), 256, 0, stream>>>(
        ctxW, ctxS, nullptr, nullptr, Wi2b, bi2, xW2, 32768, 1536, 1024);

    // GRU2 (S=128): 16 col-wgs x 4 row-groups, keep only final hidden state
    {
        const short* xWa = xW2; const short* Wpa = Wp2; const float* bha = bh2;
        short* a0 = hb0; short* a1 = hb1; short* ha = nullptr; float* hf = h2f;
        unsigned* cp = cnts + 8 * 32; int S = 128, T = 256;
        void* args[] = { (void*)&xWa, (void*)&Wpa, (void*)&bha, (void*)&a0, (void*)&a1,
                         (void*)&ha, (void*)&hf, (void*)&cp, (void*)&S, (void*)&T };
        hipError_t e = hipLaunchCooperativeKernel(
            reinterpret_cast<void*>(&gru_scan6<0>), dim3(16, 4), dim3(256), args, 0, stream);
        if (e != hipSuccess)
            gru_scan6<0><<<dim3(16, 4), 256, 0, stream>>>(xWa, Wpa, bha, a0, a1, ha, hf, cp, S, T);
    }

    final_head_k<<<128, 64, 0, stream>>>(h2f, Wf, bfv, (float*)d_out);
}

// Round 7
// 3291.017 us; speedup vs baseline: 6.7193x; 1.4198x over previous
//
#include <hip/hip_runtime.h>
#include <cstdio>

typedef __bf16 bf16x8 __attribute__((ext_vector_type(8)));
typedef float f32x4 __attribute__((ext_vector_type(4)));

#define DEV __device__ __forceinline__

DEV short f2bf(float f) {
    unsigned u = __builtin_bit_cast(unsigned, f);
    u += 0x7fffu + ((u >> 16) & 1u);   // RNE
    return (short)(u >> 16);
}
DEV float bf2f(short s) {
    unsigned u = ((unsigned)(unsigned short)s) << 16;
    return __builtin_bit_cast(float, u);
}
DEV float sigmoidf_(float x) { return 1.0f / (1.0f + __expf(-x)); }
DEV float tanhf_(float x) { float e = __expf(2.0f * x); return 1.0f - 2.0f / (e + 1.0f); }

DEV void gload_lds16(const void* g, void* l) {
    __builtin_amdgcn_global_load_lds(
        (__attribute__((address_space(1))) void*)(g),
        (__attribute__((address_space(3))) void*)(l), 16, 0, 0);
}

DEV f32x4 mfma16(bf16x8 a, bf16x8 b, f32x4 c) {
    return __builtin_amdgcn_mfma_f32_16x16x32_bf16(a, b, c, 0, 0, 0);
}

// ---------------- f32 -> bf16 convert ----------------
__global__ void f2bf_vec(const float* __restrict__ in, short* __restrict__ out, int n4) {
    int i = blockIdx.x * 256 + threadIdx.x;
    if (i >= n4) return;
    float4 v = reinterpret_cast<const float4*>(in)[i];
    short4 o;
    o.x = f2bf(v.x); o.y = f2bf(v.y); o.z = f2bf(v.z); o.w = f2bf(v.w);
    reinterpret_cast<short4*>(out)[i] = o;
}

// ---------------- pack Wh [1536][512] f32 into MFMA B-fragment order ----------------
__global__ void pack_wh(const float* __restrict__ Wh, short* __restrict__ Wp) {
    int tile = blockIdx.x, kk = blockIdx.y, l = threadIdx.x;  // 96 x 16, 64 thr
    int n = tile * 16 + (l & 15);
    int k0 = kk * 32 + (l >> 4) * 8;
    const float* src = Wh + (size_t)n * 512 + k0;
    short o[8];
#pragma unroll
    for (int e = 0; e < 8; e++) o[e] = f2bf(src[e]);
    *(int4*)(Wp + ((size_t)(tile * 16 + kk) * 64 + l) * 8) = *(int4*)o;
}

// ---------------- GEMM: C[m,n] = sum_k A[m,k] * W[n,k] + bias[n] ----------------
enum { M_XW1 = 0, M_UAW = 1, M_UAS = 2, M_XW2 = 3 };

template<int MODE>
__global__ __launch_bounds__(256) void gemm_bt(
    const short* __restrict__ Abase, const short* __restrict__ A2,
    const int* __restrict__ tok0, const int* __restrict__ tok1,
    const short* __restrict__ W, const float* __restrict__ bias,
    short* __restrict__ C, int M, int N, int K)
{
    __shared__ short Als[128 * 64];
    __shared__ short Bls[128 * 64];
    int tid = threadIdx.x;
    int m0 = blockIdx.y * 128, n0 = blockIdx.x * 128;
    int kc = (tid & 7) * 8;

    const short* arow[4];
#pragma unroll
    for (int i = 0; i < 4; i++) {
        int gm = m0 + i * 32 + (tid >> 3);
        if (MODE == M_XW1) {
            int t = gm >> 8, s = gm & 255;
            int tok = (s < 128) ? tok0[s * 256 + t] : tok1[(s - 128) * 256 + t];
            arow[i] = Abase + (size_t)tok * 512;
        } else if (MODE == M_UAW) {
            int t = gm >> 7, b = gm & 127;
            arow[i] = Abase + (size_t)tok0[b * 256 + t] * 512;
        } else if (MODE == M_UAS) {
            int t = gm >> 7, b = gm & 127;
            arow[i] = Abase + ((size_t)t * 256 + b) * 512;
        } else {
            arow[i] = Abase + (size_t)gm * 512;
        }
    }

    f32x4 acc[4][4] = {};
    int l = tid & 63, w = tid >> 6;
    int wm = (w >> 1) * 64, wn = (w & 1) * 64;

    for (int kt = 0; kt < K; kt += 64) {
#pragma unroll
        for (int i = 0; i < 4; i++) {
            const short* asrc;
            if (MODE == M_XW2) {
                int gm = m0 + i * 32 + (tid >> 3);
                const short* base = (kt < 512) ? Abase : A2;
                asrc = base + (size_t)gm * 512 + (kt & 511) + kc;
            } else {
                asrc = arow[i] + kt + kc;
            }
            gload_lds16(asrc, &Als[i * 2048 + tid * 8]);
        }
#pragma unroll
        for (int i = 0; i < 4; i++) {
            const short* bsrc = W + (size_t)(n0 + i * 32 + (tid >> 3)) * K + kt + kc;
            gload_lds16(bsrc, &Bls[i * 2048 + tid * 8]);
        }
        __syncthreads();
#pragma unroll
        for (int kk = 0; kk < 2; kk++) {
            int ko = kk * 32 + (l >> 4) * 8;
            bf16x8 af[4], bfr[4];
#pragma unroll
            for (int mi = 0; mi < 4; mi++)
                af[mi] = *(const bf16x8*)&Als[(wm + mi * 16 + (l & 15)) * 64 + ko];
#pragma unroll
            for (int ni = 0; ni < 4; ni++)
                bfr[ni] = *(const bf16x8*)&Bls[(wn + ni * 16 + (l & 15)) * 64 + ko];
#pragma unroll
            for (int mi = 0; mi < 4; mi++)
#pragma unroll
                for (int ni = 0; ni < 4; ni++)
                    acc[mi][ni] = mfma16(af[mi], bfr[ni], acc[mi][ni]);
        }
        __syncthreads();
    }
#pragma unroll
    for (int ni = 0; ni < 4; ni++) {
        int col = n0 + wn + ni * 16 + (l & 15);
        float bv = bias[col];
#pragma unroll
        for (int mi = 0; mi < 4; mi++) {
            int row0 = m0 + wm + mi * 16 + (l >> 4) * 4;
#pragma unroll
            for (int j = 0; j < 4; j++)
                C[(size_t)(row0 + j) * N + col] = f2bf(acc[mi][ni][j] + bv);
        }
    }
}

// ---------------- GRU scan v7: LDS-resident Wh, coherence-scoped data, fence-free sync ----
// Grid = (16 col-blocks of 32 cols, S/32 row-groups), 256 threads (4 waves).
// All cross-wg h traffic uses AGENT-scope RELAXED atomic load/store (sc-bit ops
// operating at the cross-XCD coherence point) -> NO buffer_wbl2 / buffer_inv in
// the loop at all. Ordering: __syncthreads before the counter add drains
// vmcnt(0), so all coherent h stores are at L3 before the add is visible;
// pollers read the counter relaxed and then load h from L3.
template<int WRITE_ALL>
__global__ __launch_bounds__(256, 1) void gru_scan7(
    const short* __restrict__ xW,   // [T][S][1536] bf16 (includes bi)
    const short* __restrict__ Wp,   // packed Wh fragments [96][16][64][8] bf16
    const float* __restrict__ bh,   // [1536]
    short* __restrict__ hb0, short* __restrict__ hb1,  // [S][512] bf16 ping-pong
    short* __restrict__ h_all,      // [T][S][512] bf16 (WRITE_ALL)
    float* __restrict__ h_final,    // [S][512] f32 (!WRITE_ALL, t==T-1)
    unsigned* __restrict__ cnt,     // per-row-group counters, stride 32 u32 (128B)
    int S, int T)
{
    __shared__ char wl[96 * 1024];   // Wh fragments [6 lg][16 kk][64 lane][16B]

    int cb = blockIdx.x;             // col block (32 cols)
    int rg = blockIdx.y;             // row group (32 rows)
    int r0 = rg * 32;
    int tid = threadIdx.x;
    int w = tid >> 6, l = tid & 63;
    int rt = w >> 1, ct = w & 1;
    int lrow = l & 15, lq = l >> 4;
    int colg = cb * 32 + ct * 16 + lrow;
    unsigned* myc = cnt + rg * 32;

    // stage Wh slice once: local gtile lg = g*2+c2 <-> global g*32 + cb*2 + c2
    for (int rr = 0; rr < 24; rr++) {
        int flat = rr * 256 + tid;               // [0, 6144) 16B chunks
        int lane = flat & 63, kk = (flat >> 6) & 15, lg = flat >> 10;
        int g = lg >> 1, c2 = lg & 1;
        gload_lds16(Wp + (((size_t)(g * 32 + cb * 2 + c2) * 16 + kk) * 64 + lane) * 8,
                    wl + flat * 16);
    }
    float bhv[3];
#pragma unroll
    for (int g = 0; g < 3; g++) bhv[g] = bh[g * 512 + colg];
    __syncthreads();   // drains Wh DMA

    for (int t = 0; t < T; t++) {
        // xW loads issued before the spin; land in registers during the wait
        short xrv[4], xzv[4], xnv[4];
        const short* xbase = xW + ((size_t)t * S + r0) * 1536 + colg;
#pragma unroll
        for (int j = 0; j < 4; j++) {
            const short* xp = xbase + (size_t)(rt * 16 + lq * 4 + j) * 1536;
            xrv[j] = xp[0]; xzv[j] = xp[512]; xnv[j] = xp[1024];
        }

        f32x4 acc[3] = {};
        float hp[4] = {};
        if (t > 0) {
            const short* hprev = ((t & 1) ? hb0 : hb1) + (size_t)r0 * 512;
            if (tid == 0) {
                unsigned tgt = 16u * (unsigned)t;
                while (__hip_atomic_load(myc, __ATOMIC_RELAXED, __HIP_MEMORY_SCOPE_AGENT) < tgt)
                    __builtin_amdgcn_s_sleep(1);
            }
            __syncthreads();
            // A fragments: coherent 8B loads straight from L3 (2 per fragment)
            bf16x8 afr[16];
            const unsigned long long* arow =
                (const unsigned long long*)(hprev + (size_t)(rt * 16 + lrow) * 512);
#pragma unroll
            for (int kk = 0; kk < 16; kk++) {
                unsigned long long lo = __hip_atomic_load(arow + kk * 8 + lq * 2,
                    __ATOMIC_RELAXED, __HIP_MEMORY_SCOPE_AGENT);
                unsigned long long hi = __hip_atomic_load(arow + kk * 8 + lq * 2 + 1,
                    __ATOMIC_RELAXED, __HIP_MEMORY_SCOPE_AGENT);
                ulonglong2 v; v.x = lo; v.y = hi;
                afr[kk] = __builtin_bit_cast(bf16x8, v);
            }
#pragma unroll
            for (int j = 0; j < 4; j++) {
                unsigned short h16 = __hip_atomic_load(
                    (const unsigned short*)hprev + (size_t)(rt * 16 + lq * 4 + j) * 512 + colg,
                    __ATOMIC_RELAXED, __HIP_MEMORY_SCOPE_AGENT);
                hp[j] = bf2f((short)h16);
            }
            // MFMA: 3 gates x 16 kk (B from LDS-resident Wh)
#pragma unroll
            for (int g = 0; g < 3; g++) {
                const char* bbase = wl + (size_t)((g * 2 + ct) * 16) * 1024 + l * 16;
#pragma unroll
                for (int kk = 0; kk < 16; kk++) {
                    bf16x8 bfr = *(const bf16x8*)(bbase + kk * 1024);
                    acc[g] = mfma16(afr[kk], bfr, acc[g]);
                }
            }
        }

        // gates + coherent h_new stores, publish, then off-chain stores
        short* hnew = (t & 1) ? hb1 : hb0;
        float hv[4]; short hbv[4];
#pragma unroll
        for (int j = 0; j < 4; j++) {
            float r = sigmoidf_(bf2f(xrv[j]) + bhv[0] + acc[0][j]);
            float z = sigmoidf_(bf2f(xzv[j]) + bhv[1] + acc[1][j]);
            float n = tanhf_(bf2f(xnv[j]) + r * (acc[2][j] + bhv[2]));
            hv[j] = (1.f - z) * n + z * hp[j];
            hbv[j] = f2bf(hv[j]);
            __hip_atomic_store(
                (unsigned short*)hnew + (size_t)(r0 + rt * 16 + lq * 4 + j) * 512 + colg,
                (unsigned short)hbv[j], __ATOMIC_RELAXED, __HIP_MEMORY_SCOPE_AGENT);
        }
        __syncthreads();   // vmcnt(0) drain: all coherent stores acked before publish
        if (tid == 0)
            __hip_atomic_fetch_add(myc, 1u, __ATOMIC_RELAXED, __HIP_MEMORY_SCOPE_AGENT);
        if (WRITE_ALL) {
#pragma unroll
            for (int j = 0; j < 4; j++)
                h_all[((size_t)t * S + r0 + rt * 16 + lq * 4 + j) * 512 + colg] = hbv[j];
        } else if (t == T - 1) {
#pragma unroll
            for (int j = 0; j < 4; j++)
                h_final[(size_t)(r0 + rt * 16 + lq * 4 + j) * 512 + colg] = hv[j];
        }
    }
}

// ---------------- per-(b) sums: u_all_sum ----------------
__global__ void embed_sum_k(const short* __restrict__ ebf, const int* __restrict__ tok,
                            float* __restrict__ out) {
    int b = blockIdx.x, d = threadIdx.x;
    float a0 = 0.f, a1 = 0.f;
    for (int t = 0; t < 256; t++) {
        const short* row = ebf + (size_t)tok[b * 256 + t] * 512;
        a0 += bf2f(row[d]); a1 += bf2f(row[d + 256]);
    }
    out[b * 512 + d] = a0; out[b * 512 + d + 256] = a1;
}
__global__ void hall_sum_k(const short* __restrict__ h_all, float* __restrict__ out) {
    int b = blockIdx.x, d = threadIdx.x;
    float a0 = 0.f, a1 = 0.f;
    for (int t = 0; t < 256; t++) {
        const short* row = h_all + ((size_t)t * 256 + b) * 512;
        a0 += bf2f(row[d]); a1 += bf2f(row[d + 256]);
    }
    out[b * 512 + d] = a0; out[b * 512 + d + 256] = a1;
}

// ---------------- dual attention combine (one wave per (t,b)) ----------------
template<int WORD>
__global__ __launch_bounds__(256) void attn_combine(
    const short* __restrict__ uA, const short* __restrict__ rsrc,
    const int* __restrict__ rtok, const float* __restrict__ usum,
    const float* __restrict__ Wv, short* __restrict__ ctx)
{
    int l = threadIdx.x & 63, w = threadIdx.x >> 6;
    int m = blockIdx.x * 4 + w;
    int t = m >> 7, b = m & 127;
    const short* rrow;
    if (WORD) rrow = rsrc + (size_t)rtok[b * 256 + t] * 512;
    else      rrow = rsrc + ((size_t)t * 256 + 128 + b) * 512;
    const short* urow = uA + (size_t)m * 512;
    int d0 = l * 8;
    short ru[8], uu[8];
    *(int4*)ru = *(const int4*)(rrow + d0);
    *(int4*)uu = *(const int4*)(urow + d0);
    float rv[8], dot = 0.f;
#pragma unroll
    for (int i = 0; i < 8; i++) { rv[i] = bf2f(ru[i]); dot += rv[i] * bf2f(uu[i]); }
#pragma unroll
    for (int off = 32; off >= 1; off >>= 1) dot += __shfl_xor(dot, off);
    float tw = tanhf_(dot);
    float e[8], se = 0.f;
#pragma unroll
    for (int i = 0; i < 8; i++) { e[i] = __expf(tw * Wv[d0 + i]); se += e[i]; }
#pragma unroll
    for (int off = 32; off >= 1; off >>= 1) se += __shfl_xor(se, off);
    float inv = 1.f / se;
    short ov[8];
#pragma unroll
    for (int i = 0; i < 8; i++) ov[i] = f2bf(e[i] * inv * usum[b * 512 + d0 + i] * rv[i]);
    *(int4*)(ctx + (size_t)m * 512 + d0) = *(int4*)ov;
}

// ---------------- final classifier + softmax ----------------
__global__ void final_head_k(const float* __restrict__ h2, const float* __restrict__ Wf,
                             const float* __restrict__ bfv, float* __restrict__ out) {
    int b = blockIdx.x, l = threadIdx.x;  // 64 threads
    float d0 = 0.f, d1 = 0.f;
    for (int k = l; k < 512; k += 64) {
        float h = h2[b * 512 + k];
        d0 += h * Wf[k];
        d1 += h * Wf[512 + k];
    }
#pragma unroll
    for (int off = 32; off >= 1; off >>= 1) { d0 += __shfl_xor(d0, off); d1 += __shfl_xor(d1, off); }
    if (l == 0) {
        float l0 = d0 + bfv[0], l1 = d1 + bfv[1];
        float mx = fmaxf(l0, l1);
        float e0 = __expf(l0 - mx), e1 = __expf(l1 - mx);
        float s = e0 + e1;
        out[b * 2] = e0 / s; out[b * 2 + 1] = e1 / s;
    }
}

extern "C" void kernel_launch(void* const* d_in, const int* in_sizes, int n_in,
                              void* d_out, int out_size, void* d_ws, size_t ws_size,
                              hipStream_t stream)
{
    const int* ask    = (const int*)d_in[0];
    const int* answer = (const int*)d_in[1];
    const int* askkw  = (const int*)d_in[2];
    const int* anskw  = (const int*)d_in[3];
    const float* embed = (const float*)d_in[4];
    const float* Wi1 = (const float*)d_in[5];
    const float* Wh1 = (const float*)d_in[6];
    const float* bi1 = (const float*)d_in[7];
    const float* bh1 = (const float*)d_in[8];
    const float* Aw  = (const float*)d_in[9];
    const float* bw  = (const float*)d_in[10];
    const float* Ww  = (const float*)d_in[11];
    const float* As  = (const float*)d_in[12];
    const float* bs  = (const float*)d_in[13];
    const float* Ws  = (const float*)d_in[14];
    const float* Wi2 = (const float*)d_in[15];
    const float* Wh2 = (const float*)d_in[16];
    const float* bi2 = (const float*)d_in[17];
    const float* bh2 = (const float*)d_in[18];
    const float* Wf  = (const float*)d_in[19];
    const float* bfv = (const float*)d_in[20];

    char* ws = (char*)d_ws;
    size_t off = 0;
    auto alloc = [&](size_t bytes) -> void* {
        void* p = (void*)(ws + off);
        off += (bytes + 255) & ~(size_t)255;
        return p;
    };
    short* embed_bf = (short*)alloc(50000ULL * 512 * 2);
    short* Wi1b = (short*)alloc(1536 * 512 * 2);
    short* Wp1  = (short*)alloc(1536 * 512 * 2);   // packed Wh1 fragments
    short* Awb  = (short*)alloc(512 * 512 * 2);
    short* Asb  = (short*)alloc(512 * 512 * 2);
    short* Wi2b = (short*)alloc(1536 * 1024 * 2);
    short* Wp2  = (short*)alloc(1536 * 512 * 2);   // packed Wh2 fragments
    char* X = (char*)alloc(201326592ULL);            // xW1 region, reused after GRU1
    short* xW1  = (short*)X;                         // [256][256][1536] bf16
    short* uA   = (short*)X;                         // [32768][512] bf16 (after GRU1)
    short* ctxW = (short*)(X + 33554432);            // [256][128][512] bf16
    short* ctxS = (short*)(X + 67108864);            // [256][128][512] bf16
    short* xW2  = (short*)(X + 100663296);           // [256][128][1536] bf16
    short* h_all = (short*)alloc(256ULL * 256 * 512 * 2);  // [t][s][512] bf16
    short* hb0 = (short*)alloc(256 * 512 * 2);
    short* hb1 = (short*)alloc(256 * 512 * 2);
    float* usumW = (float*)alloc(128 * 512 * 4);
    float* usumS = (float*)alloc(128 * 512 * 4);
    float* h2f   = (float*)alloc(128 * 512 * 4);
    unsigned* cnts = (unsigned*)alloc(12 * 128);     // 8 GRU1 + 4 GRU2 counters, 128B apart

    if (off > ws_size) {
        fprintf(stderr, "kernel_launch: workspace too small: need %zu have %zu\n", off, ws_size);
        return;
    }

    // zero sync counters (replayed on every graph launch)
    hipMemsetAsync(cnts, 0, 12 * 128, stream);

    auto cv = [&](const float* src, short* dst, int n) {
        int n4 = n / 4;
        f2bf_vec<<<(n4 + 255) / 256, 256, 0, stream>>>(src, dst, n4);
    };
    cv(embed, embed_bf, 50000 * 512);
    cv(Wi1, Wi1b, 1536 * 512);
    cv(Aw, Awb, 512 * 512);
    cv(As, Asb, 512 * 512);
    cv(Wi2, Wi2b, 1536 * 1024);
    pack_wh<<<dim3(96, 16), 64, 0, stream>>>(Wh1, Wp1);
    pack_wh<<<dim3(96, 16), 64, 0, stream>>>(Wh2, Wp2);

    // xW1 = gathered embeds @ Wi1^T + bi1, rows m = t*256 + s  (s<128: ask, else answer)
    gemm_bt<M_XW1><<<dim3(12, 512), 256, 0, stream>>>(
        embed_bf, nullptr, ask, answer, Wi1b, bi1, xW1, 65536, 1536, 512);

    // GRU1 over ask+ans combined (S=256): 16 col-wgs x 8 row-groups
    {
        const short* xWa = xW1; const short* Wpa = Wp1; const float* bha = bh1;
        short* a0 = hb0; short* a1 = hb1; short* ha = h_all; float* hf = h2f;
        unsigned* cp = cnts; int S = 256, T = 256;
        void* args[] = { (void*)&xWa, (void*)&Wpa, (void*)&bha, (void*)&a0, (void*)&a1,
                         (void*)&ha, (void*)&hf, (void*)&cp, (void*)&S, (void*)&T };
        hipError_t e = hipLaunchCooperativeKernel(
            reinterpret_cast<void*>(&gru_scan7<1>), dim3(16, 8), dim3(256), args, 0, stream);
        if (e != hipSuccess)   // fallback: plain launch (128 wgs, 1/CU -> co-resident)
            gru_scan7<1><<<dim3(16, 8), 256, 0, stream>>>(xWa, Wpa, bha, a0, a1, ha, hf, cp, S, T);
    }

    // word attention
    embed_sum_k<<<128, 256, 0, stream>>>(embed_bf, askkw, usumW);
    gemm_bt<M_UAW><<<dim3(4, 256), 256, 0, stream>>>(
        embed_bf, nullptr, askkw, nullptr, Awb, bw, uA, 32768, 512, 512);
    attn_combine<1><<<8192, 256, 0, stream>>>(uA, embed_bf, anskw, usumW, Ww, ctxW);

    // seq attention
    hall_sum_k<<<128, 256, 0, stream>>>(h_all, usumS);
    gemm_bt<M_UAS><<<dim3(4, 256), 256, 0, stream>>>(
        h_all, nullptr, nullptr, nullptr, Asb, bs, uA, 32768, 512, 512);
    attn_combine<0><<<8192, 256, 0, stream>>>(uA, h_all, nullptr, usumS, Ws, ctxS);

    // xW2 = [ctxW | ctxS] @ Wi2^T + bi2, rows m = t*128 + b
    gemm_bt<M_XW2><<<dim3(12, 256), 256, 0, stream>>>(
        ctxW, ctxS, nullptr, nullptr, Wi2b, bi2, xW2, 32768, 1536, 1024);

    // GRU2 (S=128): 16 col-wgs x 4 row-groups, keep only final hidden state
    {
        const short* xWa = xW2; const short* Wpa = Wp2; const float* bha = bh2;
        short* a0 = hb0; short* a1 = hb1; short* ha = nullptr; float* hf = h2f;
        unsigned* cp = cnts + 8 * 32; int S = 128, T = 256;
        void* args[] = { (void*)&xWa, (void*)&Wpa, (void*)&bha, (void*)&a0, (void*)&a1,
                         (void*)&ha, (void*)&hf, (void*)&cp, (void*)&S, (void*)&T };
        hipError_t e = hipLaunchCooperativeKernel(
            reinterpret_cast<void*>(&gru_scan7<0>), dim3(16, 4), dim3(256), args, 0, stream);
        if (e != hipSuccess)
            gru_scan7<0><<<dim3(16, 4), 256, 0, stream>>>(xWa, Wpa, bha, a0, a1, ha, hf, cp, S, T);
    }

    final_head_k<<<128, 64, 0, stream>>>(h2f, Wf, bfv, (float*)d_out);
}